// Round 1
// baseline (638.310 us; speedup 1.0000x reference)
//
#include <hip/hip_runtime.h>
#include <hip/hip_bf16.h>

using u16 = unsigned short;
using u32 = unsigned int;
typedef short short8 __attribute__((ext_vector_type(8)));
typedef float f32x4 __attribute__((ext_vector_type(4)));

#define B_  2
#define S_  2048
#define E_  768
#define BS_ 4096

#define L2E_ 1.44269504088896f
#define FML2_ 17.3123404906676f   // 12.0 * log2(e) fixed softmax stabilizer

__device__ __forceinline__ u16 f2bf(float f) {
  __hip_bfloat16 h = __float2bfloat16(f);
  return *reinterpret_cast<u16*>(&h);
}

__device__ __forceinline__ u32 pk2(float a, float b) {
  return (u32)f2bf(a) | ((u32)f2bf(b) << 16);
}

// async global->LDS, 16B per lane. LDS dest must be wave-uniform base + lane*16.
__device__ __forceinline__ void gld16(const void* g, void* l) {
  __builtin_amdgcn_global_load_lds(
      (const __attribute__((address_space(1))) u32*)g,
      (__attribute__((address_space(3))) u32*)l, 16, 0, 0);
}

// ---------------- conversion / misc kernels ----------------

__global__ __launch_bounds__(256) void conv_x_k(const float* __restrict__ x,
                                                u16* __restrict__ xb, int n4) {
  int i = blockIdx.x * 256 + threadIdx.x;
  if (i >= n4) return;
  float4 v = reinterpret_cast<const float4*>(x)[i];
  reinterpret_cast<uint2*>(xb)[i] = make_uint2(pk2(v.x, v.y), pk2(v.z, v.w));
}

__global__ __launch_bounds__(256) void bias_k(
    const float* rqb, const float* rkb, const float* rvb,
    const float* cqb, const float* ckb, const float* cvb,
    const float* rob, const float* cob,
    const float* rcb, const float* ccb,
    float* bqkv, float* bproj) {
  int t = blockIdx.x * 256 + threadIdx.x;
  if (t < 4608) {
    int seg = t / 768, i = t - seg * 768;
    float v = 0.f;
    if      (seg == 0) v = rqb[i] + rcb[i];   // cultural bias folds into Q bias
    else if (seg == 1) v = rkb[i];
    else if (seg == 2) v = rvb[i];
    else if (seg == 3) v = cqb[i] + ccb[i];
    else if (seg == 4) v = ckb[i];
    else               v = cvb[i];
    bqkv[t] = v;
  } else {
    int u = t - 4608;
    if (u < 1536) bproj[u] = (u < 768) ? rob[u] : cob[u - 768];
  }
}

struct TP {
  const float* src[9];
  u16* dst[9];
  int rows[9];
};

// dst[c][r] = bf16(src[r][c]); src is [rows][768]
__global__ __launch_bounds__(256) void transpose_k(TP p) {
  int mi = blockIdx.z;
  int rows = p.rows[mi];
  int r0 = blockIdx.y * 32;
  if (r0 >= rows) return;
  int c0 = blockIdx.x * 32;
  const float* src = p.src[mi];
  u16* dst = p.dst[mi];
  __shared__ float t[32][33];
  int tx = threadIdx.x & 31, ty = threadIdx.x >> 5;
#pragma unroll
  for (int d = 0; d < 4; ++d) {
    int r = ty + d * 8;
    t[r][tx] = src[(size_t)(r0 + r) * 768 + c0 + tx];
  }
  __syncthreads();
#pragma unroll
  for (int d = 0; d < 4; ++d) {
    int c = ty + d * 8;
    dst[(size_t)(c0 + c) * rows + r0 + tx] = f2bf(t[tx][c]);
  }
}

// ============ transposed GEMM: computes C^T, i.e. C[row=M][col=N] with
// A[M][K], BT[N][K]; lane's 4 acc values are CONSECUTIVE M-rows -> packed
// 8B stores. MODE 0: PROJ (bf16 -> Cout[col*ldc+row], m-split A select)
// MODE 1: FINAL (fp32 float4 -> Cout[col*ldc+row])
// MODE 2: QKVT routing (M=feature, N=token) ============

template<int MODE>
__global__ __launch_bounds__(256) void gemm_t_k(
    const u16* __restrict__ A, int lda,
    const u16* __restrict__ BT, int ldb,
    const float* __restrict__ bias, int K,
    const u16* __restrict__ A2, int msplit, int bofs,
    void* __restrict__ Cout, int ldc,
    u16* __restrict__ Qr, u16* __restrict__ Kr, u16* __restrict__ Vtr,
    u16* __restrict__ Qc, u16* __restrict__ Kc, u16* __restrict__ Vtc) {
  __shared__ u16 lA[128 * 32];
  __shared__ u16 lB[128 * 32];
  const int tid = threadIdx.x, w = tid >> 6, lane = tid & 63;
  const int quad = lane >> 4, l15 = lane & 15;
  const int m0 = blockIdx.y * 128, n0 = blockIdx.x * 128;
  if (msplit && m0 >= msplit) { A = A2 - (size_t)msplit * lda; BT += bofs; }

  const f32x4 z4 = {0.f, 0.f, 0.f, 0.f};
  f32x4 acc[4][4];
#pragma unroll
  for (int i = 0; i < 4; ++i)
#pragma unroll
    for (int j = 0; j < 4; ++j) acc[i][j] = z4;

  const int sr = w * 32 + (lane >> 2);
  const int scp = lane & 3;

  for (int kt = 0; kt < K; kt += 32) {
    int r1 = sr, r2 = sr + 16;
    int c1 = (scp - (r1 >> 2)) & 3;
    int c2 = (scp - (r2 >> 2)) & 3;
    gld16(A + (size_t)(m0 + r1) * lda + kt + c1 * 8, &lA[r1 * 32 + scp * 8]);
    gld16(A + (size_t)(m0 + r2) * lda + kt + c2 * 8, &lA[r2 * 32 + scp * 8]);
    gld16(BT + (size_t)(n0 + r1) * ldb + kt + c1 * 8, &lB[r1 * 32 + scp * 8]);
    gld16(BT + (size_t)(n0 + r2) * ldb + kt + c2 * 8, &lB[r2 * 32 + scp * 8]);
    __syncthreads();
    short8 af[4], bg[4];
#pragma unroll
    for (int i = 0; i < 4; ++i) {
      int r = (w >> 1) * 64 + i * 16 + l15;
      af[i] = *reinterpret_cast<const short8*>(&lA[r * 32 + ((quad + (r >> 2)) & 3) * 8]);
    }
#pragma unroll
    for (int j = 0; j < 4; ++j) {
      int r = (w & 1) * 64 + j * 16 + l15;
      bg[j] = *reinterpret_cast<const short8*>(&lB[r * 32 + ((quad + (r >> 2)) & 3) * 8]);
    }
#pragma unroll
    for (int i = 0; i < 4; ++i)
#pragma unroll
      for (int j = 0; j < 4; ++j)
        acc[i][j] = __builtin_amdgcn_mfma_f32_16x16x32_bf16(af[i], bg[j], acc[i][j], 0, 0, 0);
    __syncthreads();
  }

  const int seg = (MODE == 2) ? (m0 / 768) : 0;
#pragma unroll
  for (int i = 0; i < 4; ++i) {
    int f = m0 + (w >> 1) * 64 + i * 16 + quad * 4;   // M-row base (4 consecutive)
    float4 b4 = *reinterpret_cast<const float4*>(bias + f);
#pragma unroll
    for (int j = 0; j < 4; ++j) {
      int t = n0 + (w & 1) * 64 + j * 16 + l15;        // N-col
      float v0 = acc[i][j][0] + b4.x;
      float v1 = acc[i][j][1] + b4.y;
      float v2 = acc[i][j][2] + b4.z;
      float v3 = acc[i][j][3] + b4.w;
      if (MODE == 0) {
        *reinterpret_cast<uint2*>((u16*)Cout + (size_t)t * ldc + f) =
            make_uint2(pk2(v0, v1), pk2(v2, v3));
      } else if (MODE == 1) {
        *reinterpret_cast<float4*>((float*)Cout + (size_t)t * ldc + f) =
            make_float4(v0, v1, v2, v3);
      } else {
        int b = t >> 11, s = t & 2047;
        int fs = f - seg * 768;
        if (seg == 0) {
          int h = fs >> 7, d = fs & 127;
          *reinterpret_cast<uint2*>(Qr + ((size_t)(b * 6 + h) * 2048 + s) * 128 + d) =
              make_uint2(pk2(v0, v1), pk2(v2, v3));
        } else if (seg == 1) {
          int h = fs >> 7, d = fs & 127;
          *reinterpret_cast<uint2*>(Kr + ((size_t)(b * 6 + h) * 2048 + s) * 128 + d) =
              make_uint2(pk2(v0, v1), pk2(v2, v3));
        } else if (seg == 2) {
          int h = fs >> 7, d = fs & 127;
          u16* vp = Vtr + ((size_t)(b * 6 + h) * 128 + d) * 2048 + s;
          vp[0] = f2bf(v0); vp[2048] = f2bf(v1); vp[4096] = f2bf(v2); vp[6144] = f2bf(v3);
        } else if (seg == 3) {
          int h = fs / 384, d = fs - h * 384;
          *reinterpret_cast<uint2*>(Qc + ((size_t)(b * 2 + h) * 2048 + s) * 384 + d) =
              make_uint2(pk2(v0, v1), pk2(v2, v3));
        } else if (seg == 4) {
          int h = fs / 384, d = fs - h * 384;
          *reinterpret_cast<uint2*>(Kc + ((size_t)(b * 2 + h) * 2048 + s) * 384 + d) =
              make_uint2(pk2(v0, v1), pk2(v2, v3));
        } else {
          int h = fs / 384, d = fs - h * 384;
          u16* vp = Vtc + ((size_t)(b * 2 + h) * 384 + d) * 2048 + s;
          vp[0] = f2bf(v0); vp[2048] = f2bf(v1); vp[4096] = f2bf(v2); vp[6144] = f2bf(v3);
        }
      }
    }
  }
}

// ---------------- fused attention (flash-style, fixed stabilizer) ----------------
// Per block: one (head, q-tile of 128) [cultural: also a d_out block of 128].
// Loop k-chunks of 128: S^T tile = K·Q^T (MFMA template) -> p = exp2(...) into
// LDS P tile (bf16, XOR-swizzled) -> accO += Vt·P^T. Row sums accumulate in
// registers; reduced in-block at the end; O normalized and written to AO.
// LDS: lA 8KB staging + lP 32KB (first 8KB doubles as Q-staging lB) = 40KB
// -> 4 blocks/CU. No P / Lp traffic to HBM.
__global__ __launch_bounds__(256) void attn_fused_k(
    const u16* __restrict__ Qr, const u16* __restrict__ Kr,
    const u16* __restrict__ Vtr,
    const u16* __restrict__ Qc, const u16* __restrict__ Kc,
    const u16* __restrict__ Vtc,
    u16* __restrict__ AO,
    const float* __restrict__ am, const float* __restrict__ cmask,
    float sReg, float sCul) {
  const int gz = blockIdx.z;
  const int qt0 = blockIdx.x * 128;

  const u16 *Q, *K, *Vt;
  const float* cm = nullptr;
  float scl;
  int dqk, b, colbase, vrow0;
  if (gz < 12) {
    if (blockIdx.y) return;                      // regular: d_out = 128, one y-block
    Q  = Qr  + (size_t)gz * S_ * 128;
    K  = Kr  + (size_t)gz * S_ * 128;
    Vt = Vtr + (size_t)gz * 128 * S_;
    dqk = 128; b = gz / 6; scl = sReg;
    colbase = (gz % 6) * 128; vrow0 = 0;
  } else {
    const int hc = gz - 12;                      // cultural: 3 y-blocks recompute P
    Q  = Qc  + (size_t)hc * S_ * 384;
    K  = Kc  + (size_t)hc * S_ * 384;
    Vt = Vtc + (size_t)hc * 384 * S_;
    dqk = 384; b = hc >> 1; scl = sCul;
    cm = cmask + (size_t)b * S_ * S_;
    vrow0 = blockIdx.y * 128;
    colbase = 768 + (hc & 1) * 384 + vrow0;
  }

  __shared__ __align__(16) u16 lA[128 * 32];     // K/Vt staging; tail reused as lSum
  __shared__ __align__(16) u16 lP[128 * 128];    // P tile; first 8KB doubles as lB
  u16* lB = lP;

  const int tid = threadIdx.x, w = tid >> 6, lane = tid & 63;
  const int quad = lane >> 4, l15 = lane & 15;
  const int sr = w * 32 + (lane >> 2);
  const int scp = lane & 3;
  const float* amb = am + b * S_;

  const f32x4 z4 = {0.f, 0.f, 0.f, 0.f};
  f32x4 accO[4][4];
#pragma unroll
  for (int i = 0; i < 4; ++i)
#pragma unroll
    for (int j = 0; j < 4; ++j) accO[i][j] = z4;
  float lsum[4] = {0.f, 0.f, 0.f, 0.f};

  for (int kc = 0; kc < S_; kc += 128) {
    // ---------- QK^T (transposed): accS[key][query] ----------
    f32x4 accS[4][4];
#pragma unroll
    for (int i = 0; i < 4; ++i)
#pragma unroll
      for (int j = 0; j < 4; ++j) accS[i][j] = z4;

    for (int kt = 0; kt < dqk; kt += 32) {
      const int r1 = sr, r2 = sr + 16;
      const int c1 = (scp - (r1 >> 2)) & 3;
      const int c2 = (scp - (r2 >> 2)) & 3;
      gld16(K + (size_t)(kc + r1) * dqk + kt + c1 * 8, &lA[r1 * 32 + scp * 8]);
      gld16(K + (size_t)(kc + r2) * dqk + kt + c2 * 8, &lA[r2 * 32 + scp * 8]);
      gld16(Q + (size_t)(qt0 + r1) * dqk + kt + c1 * 8, &lB[r1 * 32 + scp * 8]);
      gld16(Q + (size_t)(qt0 + r2) * dqk + kt + c2 * 8, &lB[r2 * 32 + scp * 8]);
      __syncthreads();
      short8 af[4], bg[4];
#pragma unroll
      for (int i = 0; i < 4; ++i) {
        int r = (w >> 1) * 64 + i * 16 + l15;
        af[i] = *reinterpret_cast<const short8*>(&lA[r * 32 + ((quad + (r >> 2)) & 3) * 8]);
      }
#pragma unroll
      for (int j = 0; j < 4; ++j) {
        int r = (w & 1) * 64 + j * 16 + l15;
        bg[j] = *reinterpret_cast<const short8*>(&lB[r * 32 + ((quad + (r >> 2)) & 3) * 8]);
      }
#pragma unroll
      for (int i = 0; i < 4; ++i)
#pragma unroll
        for (int j = 0; j < 4; ++j)
          accS[i][j] = __builtin_amdgcn_mfma_f32_16x16x32_bf16(af[i], bg[j], accS[i][j], 0, 0, 0);
      __syncthreads();
    }

    // ---------- softmax numerator -> lP (bf16, XOR-swizzled) ----------
#pragma unroll
    for (int i = 0; i < 4; ++i) {
      const int kbl = (w >> 1) * 64 + i * 16 + quad * 4;   // 4 consecutive keys
      const int kg = kc + kbl;
      float4 a4 = *reinterpret_cast<const float4*>(amb + kg);
      float pre0 = fmaf(a4.x, L2E_, -FML2_);
      float pre1 = fmaf(a4.y, L2E_, -FML2_);
      float pre2 = fmaf(a4.z, L2E_, -FML2_);
      float pre3 = fmaf(a4.w, L2E_, -FML2_);
#pragma unroll
      for (int j = 0; j < 4; ++j) {
        const int ql = (w & 1) * 64 + j * 16 + l15;
        float c0 = pre0, c1 = pre1, c2 = pre2, c3 = pre3;
        if (cm) {
          float4 cmv = *reinterpret_cast<const float4*>(cm + (size_t)(qt0 + ql) * S_ + kg);
          c0 = fmaf(cmv.x, L2E_, c0);
          c1 = fmaf(cmv.y, L2E_, c1);
          c2 = fmaf(cmv.z, L2E_, c2);
          c3 = fmaf(cmv.w, L2E_, c3);
        }
        float p0 = exp2f(fmaf(accS[i][j][0], scl, c0));
        float p1 = exp2f(fmaf(accS[i][j][1], scl, c1));
        float p2 = exp2f(fmaf(accS[i][j][2], scl, c2));
        float p3 = exp2f(fmaf(accS[i][j][3], scl, c3));
        lsum[j] += (p0 + p1) + (p2 + p3);
        const int idx = (ql * 128 + kbl) ^ ((ql & 7) << 3);  // 16B-block XOR swizzle
        *reinterpret_cast<uint2*>(&lP[idx]) = make_uint2(pk2(p0, p1), pk2(p2, p3));
      }
    }
    __syncthreads();

    // ---------- PV: accO[d][q] += Vt · P^T (K-dim = this 128-key chunk) ----------
    for (int kt = 0; kt < 128; kt += 32) {
      const int r1 = sr, r2 = sr + 16;
      const int c1 = (scp - (r1 >> 2)) & 3;
      const int c2 = (scp - (r2 >> 2)) & 3;
      gld16(Vt + (size_t)(vrow0 + r1) * S_ + kc + kt + c1 * 8, &lA[r1 * 32 + scp * 8]);
      gld16(Vt + (size_t)(vrow0 + r2) * S_ + kc + kt + c2 * 8, &lA[r2 * 32 + scp * 8]);
      __syncthreads();
      short8 af[4], bg[4];
#pragma unroll
      for (int i = 0; i < 4; ++i) {
        int r = (w >> 1) * 64 + i * 16 + l15;
        af[i] = *reinterpret_cast<const short8*>(&lA[r * 32 + ((quad + (r >> 2)) & 3) * 8]);
      }
#pragma unroll
      for (int j = 0; j < 4; ++j) {
        int r = (w & 1) * 64 + j * 16 + l15;
        int idx = (r * 128 + kt + quad * 8) ^ ((r & 7) << 3);
        bg[j] = *reinterpret_cast<const short8*>(&lP[idx]);
      }
#pragma unroll
      for (int i = 0; i < 4; ++i)
#pragma unroll
        for (int j = 0; j < 4; ++j)
          accO[i][j] = __builtin_amdgcn_mfma_f32_16x16x32_bf16(af[i], bg[j], accO[i][j], 0, 0, 0);
      __syncthreads();
    }
  }

  // ---------- row sums: reduce over quad (shfl) then across M-half waves (LDS) ----------
  float* lSum = reinterpret_cast<float*>(lA);   // lA dead after last PV barrier
#pragma unroll
  for (int j = 0; j < 4; ++j) {
    float s = lsum[j];
    s += __shfl_xor(s, 16);
    s += __shfl_xor(s, 32);
    if (lane < 16) lSum[(w >> 1) * 128 + (w & 1) * 64 + j * 16 + lane] = s;
  }
  __syncthreads();
  float invl[4];
#pragma unroll
  for (int j = 0; j < 4; ++j) {
    const int ql = (w & 1) * 64 + j * 16 + l15;
    invl[j] = 1.f / (lSum[ql] + lSum[128 + ql]);
  }

  // ---------- normalize & store AO[token][feature] ----------
#pragma unroll
  for (int i = 0; i < 4; ++i) {
    const int feat = colbase + (w >> 1) * 64 + i * 16 + quad * 4;
#pragma unroll
    for (int j = 0; j < 4; ++j) {
      const int qg = qt0 + (w & 1) * 64 + j * 16 + l15;
      float v0 = accO[i][j][0] * invl[j];
      float v1 = accO[i][j][1] * invl[j];
      float v2 = accO[i][j][2] * invl[j];
      float v3 = accO[i][j][3] * invl[j];
      *reinterpret_cast<uint2*>(AO + ((size_t)(b * S_ + qg)) * 1536 + feat) =
          make_uint2(pk2(v0, v1), pk2(v2, v3));
    }
  }
}

// ---------------- launcher ----------------

extern "C" void kernel_launch(void* const* d_in, const int* in_sizes, int n_in,
                              void* d_out, int out_size, void* d_ws, size_t ws_size,
                              hipStream_t stream) {
  const float* x     = (const float*)d_in[0];
  const float* cmask = (const float*)d_in[1];
  const float* amask = (const float*)d_in[2];
  const float* W[8]  = { (const float*)d_in[3], (const float*)d_in[4], (const float*)d_in[5],
                         (const float*)d_in[6], (const float*)d_in[7], (const float*)d_in[8],
                         (const float*)d_in[9], (const float*)d_in[10] };
  const float* rq_b = (const float*)d_in[11];
  const float* rk_b = (const float*)d_in[12];
  const float* rv_b = (const float*)d_in[13];
  const float* ro_b = (const float*)d_in[14];
  const float* cq_b = (const float*)d_in[15];
  const float* ck_b = (const float*)d_in[16];
  const float* cv_b = (const float*)d_in[17];
  const float* co_b = (const float*)d_in[18];
  const float* r_cb = (const float*)d_in[19];
  const float* c_cb = (const float*)d_in[20];
  const float* out_w = (const float*)d_in[21];
  const float* out_b = (const float*)d_in[22];

  char* p = (char*)d_ws;
  auto carve = [&](size_t bytes) -> void* {
    void* r = (void*)p;
    p += (bytes + 255) & ~(size_t)255;
    return r;
  };
  u16* Xb    = (u16*)carve((size_t)BS_ * E_ * 2);
  u16* WqkvT = (u16*)carve((size_t)4608 * 768 * 2);
  u16* roT   = (u16*)carve((size_t)768 * 768 * 2);
  u16* coT   = (u16*)carve((size_t)768 * 768 * 2);
  u16* outwT = (u16*)carve((size_t)768 * 1536 * 2);
  float* bqkv  = (float*)carve(4608 * 4);
  float* bproj = (float*)carve(1536 * 4);
  u16* Qr  = (u16*)carve((size_t)B_ * 6 * S_ * 128 * 2);
  u16* Kr  = (u16*)carve((size_t)B_ * 6 * S_ * 128 * 2);
  u16* Vtr = (u16*)carve((size_t)B_ * 6 * S_ * 128 * 2);
  u16* Qc  = (u16*)carve((size_t)B_ * 2 * S_ * 384 * 2);
  u16* Kc  = (u16*)carve((size_t)B_ * 2 * S_ * 384 * 2);
  u16* Vtc = (u16*)carve((size_t)B_ * 2 * S_ * 384 * 2);
  u16* AO  = (u16*)carve((size_t)BS_ * 1536 * 2);
  u16* PR  = (u16*)carve((size_t)BS_ * 1536 * 2);   // proj output (bf16)

  const float sReg = 0.08838834764831845f * L2E_;
  const float sCul = 0.05103103630798288f * L2E_;

  conv_x_k<<<dim3(BS_ * E_ / 4 / 256), 256, 0, stream>>>(x, Xb, BS_ * E_ / 4);
  bias_k<<<dim3(24), 256, 0, stream>>>(rq_b, rk_b, rv_b, cq_b, ck_b, cv_b,
                                       ro_b, co_b, r_cb, c_cb, bqkv, bproj);

  TP tp;
  const int wsel[6] = {0, 1, 2, 4, 5, 6};  // rq rk rv cq ck cv
  for (int i = 0; i < 6; ++i) {
    tp.src[i] = W[wsel[i]];
    tp.dst[i] = WqkvT + (size_t)i * 768 * 768;
    tp.rows[i] = 768;
  }
  tp.src[6] = W[3]; tp.dst[6] = roT;   tp.rows[6] = 768;   // ro_w
  tp.src[7] = W[7]; tp.dst[7] = coT;   tp.rows[7] = 768;   // co_w
  tp.src[8] = out_w; tp.dst[8] = outwT; tp.rows[8] = 1536; // out_w
  transpose_k<<<dim3(24, 48, 9), 256, 0, stream>>>(tp);

  // fused QKV projection, transposed: M=4608 features, N=4096 tokens
  gemm_t_k<2><<<dim3(32, 36), 256, 0, stream>>>(
      WqkvT, 768, Xb, 768, bqkv, 768,
      (const u16*)nullptr, 0, 0, (void*)nullptr, 0,
      Qr, Kr, Vtr, Qc, Kc, Vtc);

  // fused flash-style attention: z<12 regular (y=0 only), z>=12 cultural (3 y-blocks)
  attn_fused_k<<<dim3(16, 3, 16), 256, 0, stream>>>(
      Qr, Kr, Vtr, Qc, Kc, Vtc, AO, amask, cmask, sReg, sCul);

  // merged per-branch output projections, transposed (m-split selects coT)
  gemm_t_k<0><<<dim3(32, 12), 256, 0, stream>>>(
      roT, 768, AO, 1536, bproj, 768,
      coT, 768, 768, (void*)PR, 1536,
      nullptr, nullptr, nullptr, nullptr, nullptr, nullptr);

  // final, transposed: M=768 out-features, N=4096 tokens -> fp32 float4 stores
  gemm_t_k<1><<<dim3(32, 6), 256, 0, stream>>>(
      outwT, 1536, PR, 1536, out_b, 1536,
      (const u16*)nullptr, 0, 0, d_out, 768,
      nullptr, nullptr, nullptr, nullptr, nullptr, nullptr);
}

// Round 2
// 538.187 us; speedup vs baseline: 1.1860x; 1.1860x over previous
//
#include <hip/hip_runtime.h>
#include <hip/hip_bf16.h>

using u16 = unsigned short;
using u32 = unsigned int;
typedef short short8 __attribute__((ext_vector_type(8)));
typedef float f32x4 __attribute__((ext_vector_type(4)));

#define B_  2
#define S_  2048
#define E_  768
#define BS_ 4096

#define L2E_ 1.44269504088896f
#define FML2_ 17.3123404906676f   // 12.0 * log2(e) fixed softmax stabilizer

__device__ __forceinline__ u16 f2bf(float f) {
  __hip_bfloat16 h = __float2bfloat16(f);
  return *reinterpret_cast<u16*>(&h);
}

__device__ __forceinline__ u32 pk2(float a, float b) {
  return (u32)f2bf(a) | ((u32)f2bf(b) << 16);
}

// async global->LDS, 16B per lane. LDS dest must be wave-uniform base + lane*16.
__device__ __forceinline__ void gld16(const void* g, void* l) {
  __builtin_amdgcn_global_load_lds(
      (const __attribute__((address_space(1))) u32*)g,
      (__attribute__((address_space(3))) u32*)l, 16, 0, 0);
}

// ---------------- conversion / misc kernels ----------------

__global__ __launch_bounds__(256) void conv_x_k(const float* __restrict__ x,
                                                u16* __restrict__ xb, int n4) {
  int i = blockIdx.x * 256 + threadIdx.x;
  if (i >= n4) return;
  float4 v = reinterpret_cast<const float4*>(x)[i];
  reinterpret_cast<uint2*>(xb)[i] = make_uint2(pk2(v.x, v.y), pk2(v.z, v.w));
}

__global__ __launch_bounds__(256) void bias_k(
    const float* rqb, const float* rkb, const float* rvb,
    const float* cqb, const float* ckb, const float* cvb,
    const float* rob, const float* cob,
    const float* rcb, const float* ccb,
    float* bqkv, float* bproj) {
  int t = blockIdx.x * 256 + threadIdx.x;
  if (t < 4608) {
    int seg = t / 768, i = t - seg * 768;
    float v = 0.f;
    if      (seg == 0) v = rqb[i] + rcb[i];   // cultural bias folds into Q bias
    else if (seg == 1) v = rkb[i];
    else if (seg == 2) v = rvb[i];
    else if (seg == 3) v = cqb[i] + ccb[i];
    else if (seg == 4) v = ckb[i];
    else               v = cvb[i];
    bqkv[t] = v;
  } else {
    int u = t - 4608;
    if (u < 1536) bproj[u] = (u < 768) ? rob[u] : cob[u - 768];
  }
}

struct TP {
  const float* src[9];
  u16* dst[9];
  int rows[9];
};

// dst[c][r] = bf16(src[r][c]); src is [rows][768]
__global__ __launch_bounds__(256) void transpose_k(TP p) {
  int mi = blockIdx.z;
  int rows = p.rows[mi];
  int r0 = blockIdx.y * 32;
  if (r0 >= rows) return;
  int c0 = blockIdx.x * 32;
  const float* src = p.src[mi];
  u16* dst = p.dst[mi];
  __shared__ float t[32][33];
  int tx = threadIdx.x & 31, ty = threadIdx.x >> 5;
#pragma unroll
  for (int d = 0; d < 4; ++d) {
    int r = ty + d * 8;
    t[r][tx] = src[(size_t)(r0 + r) * 768 + c0 + tx];
  }
  __syncthreads();
#pragma unroll
  for (int d = 0; d < 4; ++d) {
    int c = ty + d * 8;
    dst[(size_t)(c0 + c) * rows + r0 + tx] = f2bf(t[tx][c]);
  }
}

// ============ transposed GEMM: computes C^T, i.e. C[row=M][col=N] with
// A[M][K], BT[N][K]; lane's 4 acc values are CONSECUTIVE M-rows -> packed
// 8B stores. MODE 0: PROJ (bf16 -> Cout[col*ldc+row], m-split A select)
// MODE 1: FINAL (fp32 float4 -> Cout[col*ldc+row])
// MODE 2: QKVT routing (M=feature, N=token) ============

template<int MODE>
__global__ __launch_bounds__(256) void gemm_t_k(
    const u16* __restrict__ A, int lda,
    const u16* __restrict__ BT, int ldb,
    const float* __restrict__ bias, int K,
    const u16* __restrict__ A2, int msplit, int bofs,
    void* __restrict__ Cout, int ldc,
    u16* __restrict__ Qr, u16* __restrict__ Kr, u16* __restrict__ Vtr,
    u16* __restrict__ Qc, u16* __restrict__ Kc, u16* __restrict__ Vtc) {
  __shared__ u16 lA[128 * 32];
  __shared__ u16 lB[128 * 32];
  const int tid = threadIdx.x, w = tid >> 6, lane = tid & 63;
  const int quad = lane >> 4, l15 = lane & 15;
  const int m0 = blockIdx.y * 128, n0 = blockIdx.x * 128;
  if (msplit && m0 >= msplit) { A = A2 - (size_t)msplit * lda; BT += bofs; }

  const f32x4 z4 = {0.f, 0.f, 0.f, 0.f};
  f32x4 acc[4][4];
#pragma unroll
  for (int i = 0; i < 4; ++i)
#pragma unroll
    for (int j = 0; j < 4; ++j) acc[i][j] = z4;

  const int sr = w * 32 + (lane >> 2);
  const int scp = lane & 3;

  for (int kt = 0; kt < K; kt += 32) {
    int r1 = sr, r2 = sr + 16;
    int c1 = (scp - (r1 >> 2)) & 3;
    int c2 = (scp - (r2 >> 2)) & 3;
    gld16(A + (size_t)(m0 + r1) * lda + kt + c1 * 8, &lA[r1 * 32 + scp * 8]);
    gld16(A + (size_t)(m0 + r2) * lda + kt + c2 * 8, &lA[r2 * 32 + scp * 8]);
    gld16(BT + (size_t)(n0 + r1) * ldb + kt + c1 * 8, &lB[r1 * 32 + scp * 8]);
    gld16(BT + (size_t)(n0 + r2) * ldb + kt + c2 * 8, &lB[r2 * 32 + scp * 8]);
    __syncthreads();
    short8 af[4], bg[4];
#pragma unroll
    for (int i = 0; i < 4; ++i) {
      int r = (w >> 1) * 64 + i * 16 + l15;
      af[i] = *reinterpret_cast<const short8*>(&lA[r * 32 + ((quad + (r >> 2)) & 3) * 8]);
    }
#pragma unroll
    for (int j = 0; j < 4; ++j) {
      int r = (w & 1) * 64 + j * 16 + l15;
      bg[j] = *reinterpret_cast<const short8*>(&lB[r * 32 + ((quad + (r >> 2)) & 3) * 8]);
    }
#pragma unroll
    for (int i = 0; i < 4; ++i)
#pragma unroll
      for (int j = 0; j < 4; ++j)
        acc[i][j] = __builtin_amdgcn_mfma_f32_16x16x32_bf16(af[i], bg[j], acc[i][j], 0, 0, 0);
    __syncthreads();
  }

  const int seg = (MODE == 2) ? (m0 / 768) : 0;
#pragma unroll
  for (int i = 0; i < 4; ++i) {
    int f = m0 + (w >> 1) * 64 + i * 16 + quad * 4;   // M-row base (4 consecutive)
    float4 b4 = *reinterpret_cast<const float4*>(bias + f);
#pragma unroll
    for (int j = 0; j < 4; ++j) {
      int t = n0 + (w & 1) * 64 + j * 16 + l15;        // N-col
      float v0 = acc[i][j][0] + b4.x;
      float v1 = acc[i][j][1] + b4.y;
      float v2 = acc[i][j][2] + b4.z;
      float v3 = acc[i][j][3] + b4.w;
      if (MODE == 0) {
        *reinterpret_cast<uint2*>((u16*)Cout + (size_t)t * ldc + f) =
            make_uint2(pk2(v0, v1), pk2(v2, v3));
      } else if (MODE == 1) {
        *reinterpret_cast<float4*>((float*)Cout + (size_t)t * ldc + f) =
            make_float4(v0, v1, v2, v3);
      } else {
        int b = t >> 11, s = t & 2047;
        int fs = f - seg * 768;
        if (seg == 0) {
          int h = fs >> 7, d = fs & 127;
          *reinterpret_cast<uint2*>(Qr + ((size_t)(b * 6 + h) * 2048 + s) * 128 + d) =
              make_uint2(pk2(v0, v1), pk2(v2, v3));
        } else if (seg == 1) {
          int h = fs >> 7, d = fs & 127;
          *reinterpret_cast<uint2*>(Kr + ((size_t)(b * 6 + h) * 2048 + s) * 128 + d) =
              make_uint2(pk2(v0, v1), pk2(v2, v3));
        } else if (seg == 2) {
          int h = fs >> 7, d = fs & 127;
          u16* vp = Vtr + ((size_t)(b * 6 + h) * 128 + d) * 2048 + s;
          vp[0] = f2bf(v0); vp[2048] = f2bf(v1); vp[4096] = f2bf(v2); vp[6144] = f2bf(v3);
        } else if (seg == 3) {
          int h = fs / 384, d = fs - h * 384;
          *reinterpret_cast<uint2*>(Qc + ((size_t)(b * 2 + h) * 2048 + s) * 384 + d) =
              make_uint2(pk2(v0, v1), pk2(v2, v3));
        } else if (seg == 4) {
          int h = fs / 384, d = fs - h * 384;
          *reinterpret_cast<uint2*>(Kc + ((size_t)(b * 2 + h) * 2048 + s) * 384 + d) =
              make_uint2(pk2(v0, v1), pk2(v2, v3));
        } else {
          int h = fs / 384, d = fs - h * 384;
          u16* vp = Vtc + ((size_t)(b * 2 + h) * 384 + d) * 2048 + s;
          vp[0] = f2bf(v0); vp[2048] = f2bf(v1); vp[4096] = f2bf(v2); vp[6144] = f2bf(v3);
        }
      }
    }
  }
}

// ---------------- fused attention v2 ----------------
// Whole-chunk LDS tiles, 4 barriers/chunk (regular), K-split KR=2 with fp32
// partial O + partial row-sums. LDS = 2 x 32KB (bufA: K->P, bufB: Q-sub/V).
// XOR swizzle: 16B col-slot s stored at s^(row&7); gld16 dest linear, global
// source pre-swizzled; ds_read applies same XOR.
#define KR_ 2

__device__ __forceinline__ void stage128(const u16* __restrict__ src, int srcStride,
                                         u16* buf, int w, int lane) {
  const int rl = lane >> 4;          // row within 4-row group
  const int cg0 = lane & 15;         // 16B col-group
#pragma unroll
  for (int it = 0; it < 8; ++it) {
    int r0 = w * 32 + it * 4;
    int row = r0 + rl;
    int cg = cg0 ^ (row & 7);        // pre-swizzled source column
    gld16(src + (size_t)row * srcStride + cg * 8, buf + r0 * 128 + lane * 8);
  }
}

__device__ __forceinline__ short8 rdfrag(const u16* buf, int r, int kt, int quad) {
  int slot = (((kt >> 3) + quad) ^ (r & 7)) & 15;
  return *reinterpret_cast<const short8*>(buf + r * 128 + slot * 8);
}

__global__ __launch_bounds__(256, 2) void attn_fused2_k(
    const u16* __restrict__ Qr, const u16* __restrict__ Kr,
    const u16* __restrict__ Vtr,
    const u16* __restrict__ Qc, const u16* __restrict__ Kc,
    const u16* __restrict__ Vtc,
    float* __restrict__ OP, float* __restrict__ Ls,
    const float* __restrict__ am, const float* __restrict__ cmask,
    float sReg, float sCul) {
  const int zz = blockIdx.z;
  const int gz = zz >> 1, kr = zz & 1;
  const int qt0 = blockIdx.x * 128;

  const u16 *Q, *K, *Vt;
  const float* cm = nullptr;
  float scl;
  int b, colbase, vrow0, hz;
  bool reg;
  if (gz < 12) {
    if (blockIdx.y) return;                    // regular: d_out = 128, one y-block
    reg = true;
    Q  = Qr  + (size_t)gz * S_ * 128;
    K  = Kr  + (size_t)gz * S_ * 128;
    Vt = Vtr + (size_t)gz * 128 * S_;
    b = gz / 6; scl = sReg; hz = gz;
    colbase = (gz % 6) * 128; vrow0 = 0;
  } else {
    reg = false;
    const int hc = gz - 12;                    // cultural: 3 y-blocks recompute P
    Q  = Qc  + (size_t)hc * S_ * 384;
    K  = Kc  + (size_t)hc * S_ * 384;
    Vt = Vtc + (size_t)hc * 384 * S_;
    b = hc >> 1; scl = sCul; hz = 12 + hc;
    cm = cmask + (size_t)b * S_ * S_;
    vrow0 = blockIdx.y * 128;
    colbase = 768 + (hc & 1) * 384 + vrow0;
  }

  __shared__ __align__(16) u16 bufA[128 * 128];   // K-tile -> P-tile
  __shared__ __align__(16) u16 bufB[128 * 128];   // Q-sub (cul) / V-tile; tail: lSum

  const int tid = threadIdx.x, w = tid >> 6, lane = tid & 63;
  const int quad = lane >> 4, l15 = lane & 15;
  const int rAb = (w >> 1) * 64 + l15;            // A-frag row base (m)
  const int rBb = (w & 1) * 64 + l15;             // B-frag row base (n)
  const float* amb = am + b * S_;

  const f32x4 z4 = {0.f, 0.f, 0.f, 0.f};
  f32x4 accO[4][4];
#pragma unroll
  for (int i = 0; i < 4; ++i)
#pragma unroll
    for (int j = 0; j < 4; ++j) accO[i][j] = z4;
  float lsum[4] = {0.f, 0.f, 0.f, 0.f};

  // regular: Q fragments to registers once (stage via bufA)
  short8 qf[4][4];
  if (reg) {
    stage128(Q + (size_t)qt0 * 128, 128, bufA, w, lane);
    __syncthreads();
#pragma unroll
    for (int kt4 = 0; kt4 < 4; ++kt4)
#pragma unroll
      for (int j = 0; j < 4; ++j)
        qf[kt4][j] = rdfrag(bufA, rBb + j * 16, kt4 * 32, quad);
    __syncthreads();
  }

  for (int ck = 0; ck < 8; ++ck) {
    const int kc = kr * 1024 + ck * 128;
    f32x4 accS[4][4];
#pragma unroll
    for (int i = 0; i < 4; ++i)
#pragma unroll
      for (int j = 0; j < 4; ++j) accS[i][j] = z4;

    if (reg) {
      // stage K-chunk + V-chunk together, then barrier-free QK
      stage128(K + (size_t)kc * 128, 128, bufA, w, lane);
      stage128(Vt + (size_t)vrow0 * S_ + kc, S_, bufB, w, lane);
      __syncthreads();
#pragma unroll
      for (int kt = 0; kt < 128; kt += 32) {
        short8 af[4];
#pragma unroll
        for (int i = 0; i < 4; ++i) af[i] = rdfrag(bufA, rAb + i * 16, kt, quad);
#pragma unroll
        for (int i = 0; i < 4; ++i)
#pragma unroll
          for (int j = 0; j < 4; ++j)
            accS[i][j] = __builtin_amdgcn_mfma_f32_16x16x32_bf16(
                af[i], qf[kt >> 5][j], accS[i][j], 0, 0, 0);
      }
      __syncthreads();    // bufA consumed -> P may overwrite
    } else {
      // cultural: 3 d-slices of K-sub + Q-sub
      for (int s = 0; s < 3; ++s) {
        stage128(K + (size_t)kc * 384 + s * 128, 384, bufA, w, lane);
        stage128(Q + (size_t)qt0 * 384 + s * 128, 384, bufB, w, lane);
        __syncthreads();
#pragma unroll
        for (int kt = 0; kt < 128; kt += 32) {
          short8 af[4], bg[4];
#pragma unroll
          for (int i = 0; i < 4; ++i) af[i] = rdfrag(bufA, rAb + i * 16, kt, quad);
#pragma unroll
          for (int j = 0; j < 4; ++j) bg[j] = rdfrag(bufB, rBb + j * 16, kt, quad);
#pragma unroll
          for (int i = 0; i < 4; ++i)
#pragma unroll
            for (int j = 0; j < 4; ++j)
              accS[i][j] = __builtin_amdgcn_mfma_f32_16x16x32_bf16(
                  af[i], bg[j], accS[i][j], 0, 0, 0);
        }
        __syncthreads();
      }
      // issue V loads early; latency hides under P epilogue
      stage128(Vt + (size_t)vrow0 * S_ + kc, S_, bufB, w, lane);
    }

    // ---------- P = exp2(accS*scl + masks) -> bufA (swizzled bf16) ----------
#pragma unroll
    for (int i = 0; i < 4; ++i) {
      const int kbl = (w >> 1) * 64 + i * 16 + quad * 4;   // 4 consecutive keys
      const int kg = kc + kbl;
      float4 a4 = *reinterpret_cast<const float4*>(amb + kg);
      float pre0 = fmaf(a4.x, L2E_, -FML2_);
      float pre1 = fmaf(a4.y, L2E_, -FML2_);
      float pre2 = fmaf(a4.z, L2E_, -FML2_);
      float pre3 = fmaf(a4.w, L2E_, -FML2_);
      const int slot = (kbl >> 3);
#pragma unroll
      for (int j = 0; j < 4; ++j) {
        const int ql = (w & 1) * 64 + j * 16 + l15;
        float c0 = pre0, c1 = pre1, c2 = pre2, c3 = pre3;
        if (!reg) {
          float4 cmv = *reinterpret_cast<const float4*>(cm + (size_t)(qt0 + ql) * S_ + kg);
          c0 = fmaf(cmv.x, L2E_, c0);
          c1 = fmaf(cmv.y, L2E_, c1);
          c2 = fmaf(cmv.z, L2E_, c2);
          c3 = fmaf(cmv.w, L2E_, c3);
        }
        float p0 = exp2f(fmaf(accS[i][j][0], scl, c0));
        float p1 = exp2f(fmaf(accS[i][j][1], scl, c1));
        float p2 = exp2f(fmaf(accS[i][j][2], scl, c2));
        float p3 = exp2f(fmaf(accS[i][j][3], scl, c3));
        lsum[j] += (p0 + p1) + (p2 + p3);
        *reinterpret_cast<uint2*>(
            &bufA[ql * 128 + (slot ^ (ql & 7)) * 8 + (quad & 1) * 4]) =
            make_uint2(pk2(p0, p1), pk2(p2, p3));
      }
    }
    __syncthreads();    // P visible; V vmcnt drained

    // ---------- PV: accO[d][q] += V(bufB) . P(bufA)^T ----------
#pragma unroll
    for (int kt = 0; kt < 128; kt += 32) {
      short8 af[4], bg[4];
#pragma unroll
      for (int i = 0; i < 4; ++i) af[i] = rdfrag(bufB, rAb + i * 16, kt, quad);
#pragma unroll
      for (int j = 0; j < 4; ++j) bg[j] = rdfrag(bufA, rBb + j * 16, kt, quad);
#pragma unroll
      for (int i = 0; i < 4; ++i)
#pragma unroll
        for (int j = 0; j < 4; ++j)
          accO[i][j] = __builtin_amdgcn_mfma_f32_16x16x32_bf16(
              af[i], bg[j], accO[i][j], 0, 0, 0);
    }
    __syncthreads();    // buffers reusable next chunk
  }

  // ---------- partial row sums -> Ls[kr][hz][q] (y==0 blocks only) ----------
  float* lSum = reinterpret_cast<float*>(bufB);
#pragma unroll
  for (int j = 0; j < 4; ++j) {
    float s = lsum[j];
    s += __shfl_xor(s, 16);
    s += __shfl_xor(s, 32);
    if (lane < 16) lSum[(w >> 1) * 128 + (w & 1) * 64 + j * 16 + lane] = s;
  }
  __syncthreads();
  if (blockIdx.y == 0 && tid < 128)
    Ls[((size_t)kr * 16 + hz) * S_ + qt0 + tid] = lSum[tid] + lSum[128 + tid];

  // ---------- store unnormalized fp32 O-partials ----------
#pragma unroll
  for (int i = 0; i < 4; ++i) {
    const int feat = colbase + (w >> 1) * 64 + i * 16 + quad * 4;
#pragma unroll
    for (int j = 0; j < 4; ++j) {
      const int qg = qt0 + (w & 1) * 64 + j * 16 + l15;
      *reinterpret_cast<float4*>(
          OP + ((size_t)kr * BS_ + (size_t)b * S_ + qg) * 1536 + feat) =
          make_float4(accO[i][j][0], accO[i][j][1], accO[i][j][2], accO[i][j][3]);
    }
  }
}

// combine KR partials: AO[t][f] = (OP0+OP1) / (Ls0+Ls1)
__global__ __launch_bounds__(256) void attn_red_k(
    const float* __restrict__ OP, const float* __restrict__ Ls,
    u16* __restrict__ AO) {
  int idx = blockIdx.x * 256 + threadIdx.x;     // BS_*384 threads, 4 feats each
  int t = idx / 384, f = (idx - t * 384) * 4;
  int b = t >> 11, q = t & 2047;
  int hz;
  if (f < 768) hz = b * 6 + (f >> 7);
  else         hz = 12 + b * 2 + (f >= 1152 ? 1 : 0);
  float inv = 1.f / (Ls[(size_t)hz * S_ + q] + Ls[((size_t)16 + hz) * S_ + q]);
  float4 p0 = *reinterpret_cast<const float4*>(OP + (size_t)t * 1536 + f);
  float4 p1 = *reinterpret_cast<const float4*>(OP + ((size_t)BS_ + t) * 1536 + f);
  float v0 = (p0.x + p1.x) * inv;
  float v1 = (p0.y + p1.y) * inv;
  float v2 = (p0.z + p1.z) * inv;
  float v3 = (p0.w + p1.w) * inv;
  *reinterpret_cast<uint2*>(AO + (size_t)t * 1536 + f) =
      make_uint2(pk2(v0, v1), pk2(v2, v3));
}

// ---------------- launcher ----------------

extern "C" void kernel_launch(void* const* d_in, const int* in_sizes, int n_in,
                              void* d_out, int out_size, void* d_ws, size_t ws_size,
                              hipStream_t stream) {
  const float* x     = (const float*)d_in[0];
  const float* cmask = (const float*)d_in[1];
  const float* amask = (const float*)d_in[2];
  const float* W[8]  = { (const float*)d_in[3], (const float*)d_in[4], (const float*)d_in[5],
                         (const float*)d_in[6], (const float*)d_in[7], (const float*)d_in[8],
                         (const float*)d_in[9], (const float*)d_in[10] };
  const float* rq_b = (const float*)d_in[11];
  const float* rk_b = (const float*)d_in[12];
  const float* rv_b = (const float*)d_in[13];
  const float* ro_b = (const float*)d_in[14];
  const float* cq_b = (const float*)d_in[15];
  const float* ck_b = (const float*)d_in[16];
  const float* cv_b = (const float*)d_in[17];
  const float* co_b = (const float*)d_in[18];
  const float* r_cb = (const float*)d_in[19];
  const float* c_cb = (const float*)d_in[20];
  const float* out_w = (const float*)d_in[21];
  const float* out_b = (const float*)d_in[22];

  char* p = (char*)d_ws;
  auto carve = [&](size_t bytes) -> void* {
    void* r = (void*)p;
    p += (bytes + 255) & ~(size_t)255;
    return r;
  };
  u16* Xb    = (u16*)carve((size_t)BS_ * E_ * 2);
  u16* WqkvT = (u16*)carve((size_t)4608 * 768 * 2);
  u16* roT   = (u16*)carve((size_t)768 * 768 * 2);
  u16* coT   = (u16*)carve((size_t)768 * 768 * 2);
  u16* outwT = (u16*)carve((size_t)768 * 1536 * 2);
  float* bqkv  = (float*)carve(4608 * 4);
  float* bproj = (float*)carve(1536 * 4);
  u16* Qr  = (u16*)carve((size_t)B_ * 6 * S_ * 128 * 2);
  u16* Kr  = (u16*)carve((size_t)B_ * 6 * S_ * 128 * 2);
  u16* Vtr = (u16*)carve((size_t)B_ * 6 * S_ * 128 * 2);
  u16* Qc  = (u16*)carve((size_t)B_ * 2 * S_ * 384 * 2);
  u16* Kc  = (u16*)carve((size_t)B_ * 2 * S_ * 384 * 2);
  u16* Vtc = (u16*)carve((size_t)B_ * 2 * S_ * 384 * 2);
  u16* AO  = (u16*)carve((size_t)BS_ * 1536 * 2);
  u16* PR  = (u16*)carve((size_t)BS_ * 1536 * 2);            // proj output (bf16)
  float* OP = (float*)carve((size_t)KR_ * BS_ * 1536 * 4);   // fp32 O partials
  float* Ls = (float*)carve((size_t)KR_ * 16 * S_ * 4);      // partial row sums

  const float sReg = 0.08838834764831845f * L2E_;
  const float sCul = 0.05103103630798288f * L2E_;

  conv_x_k<<<dim3(BS_ * E_ / 4 / 256), 256, 0, stream>>>(x, Xb, BS_ * E_ / 4);
  bias_k<<<dim3(24), 256, 0, stream>>>(rq_b, rk_b, rv_b, cq_b, ck_b, cv_b,
                                       ro_b, co_b, r_cb, c_cb, bqkv, bproj);

  TP tp;
  const int wsel[6] = {0, 1, 2, 4, 5, 6};  // rq rk rv cq ck cv
  for (int i = 0; i < 6; ++i) {
    tp.src[i] = W[wsel[i]];
    tp.dst[i] = WqkvT + (size_t)i * 768 * 768;
    tp.rows[i] = 768;
  }
  tp.src[6] = W[3]; tp.dst[6] = roT;   tp.rows[6] = 768;   // ro_w
  tp.src[7] = W[7]; tp.dst[7] = coT;   tp.rows[7] = 768;   // co_w
  tp.src[8] = out_w; tp.dst[8] = outwT; tp.rows[8] = 1536; // out_w
  transpose_k<<<dim3(24, 48, 9), 256, 0, stream>>>(tp);

  // fused QKV projection, transposed: M=4608 features, N=4096 tokens
  gemm_t_k<2><<<dim3(32, 36), 256, 0, stream>>>(
      WqkvT, 768, Xb, 768, bqkv, 768,
      (const u16*)nullptr, 0, 0, (void*)nullptr, 0,
      Qr, Kr, Vtr, Qc, Kc, Vtc);

  // fused flash attention v2: z packs (head-config, kr); y = cultural d-slice
  attn_fused2_k<<<dim3(16, 3, 16 * KR_), 256, 0, stream>>>(
      Qr, Kr, Vtr, Qc, Kc, Vtc, OP, Ls, amask, cmask, sReg, sCul);
  attn_red_k<<<dim3(BS_ * 384 / 256), 256, 0, stream>>>(OP, Ls, AO);

  // merged per-branch output projections, transposed (m-split selects coT)
  gemm_t_k<0><<<dim3(32, 12), 256, 0, stream>>>(
      roT, 768, AO, 1536, bproj, 768,
      coT, 768, 768, (void*)PR, 1536,
      nullptr, nullptr, nullptr, nullptr, nullptr, nullptr);

  // final, transposed: M=768 out-features, N=4096 tokens -> fp32 float4 stores
  gemm_t_k<1><<<dim3(32, 6), 256, 0, stream>>>(
      outwT, 1536, PR, 1536, out_b, 1536,
      (const u16*)nullptr, 0, 0, d_out, 768,
      nullptr, nullptr, nullptr, nullptr, nullptr, nullptr);
}